// Round 1
// baseline (352.107 us; speedup 1.0000x reference)
//
#include <hip/hip_runtime.h>
#include <stdint.h>

#define LDIM 1024
#define DDIM 256
#define FDIM 32
#define NSEG 64
#define BM 128
#define BK 64

typedef __attribute__((ext_vector_type(4))) float f32x4;
typedef __attribute__((ext_vector_type(8))) short short8;
typedef __attribute__((ext_vector_type(4))) unsigned int u32x4;

__device__ __forceinline__ unsigned int pk2bf(float a, float b) {
  union { float f; unsigned int u; } x, y; x.f = a; y.f = b;
  unsigned int ua = x.u + 0x7FFFu + ((x.u >> 16) & 1u);
  unsigned int ub = y.u + 0x7FFFu + ((y.u >> 16) & 1u);
  return (ua >> 16) | (ub & 0xFFFF0000u);
}

__device__ __forceinline__ unsigned short f2bf(float f) {
  union { float f; unsigned int u; } v; v.f = f;
  unsigned int r = v.u + 0x7FFFu + ((v.u >> 16) & 1u);
  return (unsigned short)(r >> 16);
}

// ---- prep: W1^T (bf16) rows 0..255, (W1@Wa1)^T rows 256..287 into ws ----
__global__ void prep_w1t(const float* __restrict__ W1, const float* __restrict__ Wa1,
                         unsigned short* __restrict__ w1t) {
  __shared__ float rowf[DDIM];
  const int k = blockIdx.x;
  const int t = threadIdx.x;
  float v = W1[(size_t)k * DDIM + t];
  rowf[t] = v;
  w1t[(size_t)t * LDIM + k] = f2bf(v);
  __syncthreads();
  if (t < FDIM) {
    float a = 0.f;
    for (int c = 0; c < DDIM; ++c) a += rowf[c] * Wa1[c * FDIM + t];
    w1t[(size_t)(DDIM + t) * LDIM + k] = f2bf(a);
  }
}

// ---- prep: zero accumulators, bz = b1@Wa1 + ba1 ----
__global__ void prep_misc(const float* __restrict__ b1, const float* __restrict__ Wa1,
                          const float* __restrict__ ba1, float* __restrict__ bz,
                          float* __restrict__ acc_eh, float* __restrict__ accE) {
  const int b = blockIdx.x, t = threadIdx.x;
  acc_eh[b * DDIM + t] = 0.f;
  if (t == 0) accE[b] = 0.f;
  if (b == 0 && t < FDIM) {
    float a = ba1[t];
    for (int c = 0; c < DDIM; ++c) a += b1[c] * Wa1[c * FDIM + t];
    bz[t] = a;
  }
}

// ---- main fused kernel: GEMM(bf16 MFMA) + attention logits + segment accum ----
__global__ __launch_bounds__(512) void fused_main(
    const float* __restrict__ x, const int* __restrict__ idxs,
    const unsigned short* __restrict__ w1t, const float* __restrict__ bz,
    const float* __restrict__ Wa2, const float* __restrict__ ba2,
    float* __restrict__ acc_eh, float* __restrict__ accE)
{
  __shared__ __align__(16) unsigned short xlds[BM][72];      // padded: 72 bf16/row
  __shared__ __align__(16) unsigned char blds[320 * 128];    // 320 rows x 128B, XOR-swizzled
  __shared__ float logit_s[BM];
  __shared__ float e_s[BM];
  __shared__ int seg_s[BM];

  const int tid = threadIdx.x;
  const int lane = tid & 63;
  const int wid = tid >> 6;
  const int wr = wid >> 2;        // 0..1 : row half
  const int wc = wid & 3;         // 0..3 : col quarter
  const int g = lane >> 4;
  const int cl = lane & 15;
  const int row0 = blockIdx.x * BM;
  const int zf = (wc < 2) ? wc : -1;   // z-fragment duty

  if (tid < BM) { seg_s[tid] = idxs[row0 + tid]; logit_s[tid] = 0.f; }

  f32x4 acc[4][4];
  f32x4 zacc[4];
  const f32x4 zero4 = {0.f, 0.f, 0.f, 0.f};
  #pragma unroll
  for (int m = 0; m < 4; ++m) {
    zacc[m] = zero4;
    #pragma unroll
    for (int n = 0; n < 4; ++n) acc[m][n] = zero4;
  }

  const int arow = tid >> 2;
  const int aq = tid & 3;
  const char* w1tb = (const char*)w1t;

  f32x4 ra[4], rb[4];
  {
    const float* gx = x + (size_t)(row0 + arow) * LDIM + aq * 16;
    ra[0] = *(const f32x4*)(gx);
    ra[1] = *(const f32x4*)(gx + 4);
    ra[2] = *(const f32x4*)(gx + 8);
    ra[3] = *(const f32x4*)(gx + 12);
  }

  auto do_iter = [&](int kt, f32x4 (&rc)[4], f32x4 (&rn)[4]) {
    __syncthreads();                       // previous tile consumed
    // A: regs -> bf16 -> LDS
    u32x4 p0, p1;
    p0[0] = pk2bf(rc[0][0], rc[0][1]); p0[1] = pk2bf(rc[0][2], rc[0][3]);
    p0[2] = pk2bf(rc[1][0], rc[1][1]); p0[3] = pk2bf(rc[1][2], rc[1][3]);
    p1[0] = pk2bf(rc[2][0], rc[2][1]); p1[1] = pk2bf(rc[2][2], rc[2][3]);
    p1[2] = pk2bf(rc[3][0], rc[3][1]); p1[3] = pk2bf(rc[3][2], rc[3][3]);
    *(u32x4*)&xlds[arow][aq * 16] = p0;
    *(u32x4*)&xlds[arow][aq * 16 + 8] = p1;
    // B: async global->LDS, source pre-inverse-swizzled so swizzled reads are correct
    #pragma unroll
    for (int j = 0; j < 5; ++j) {
      int idx = j * 512 + tid;
      int brow = idx >> 3;
      int bcolb = (idx & 7) << 4;
      int srcb = (brow << 11) + (kt << 7) + (bcolb ^ ((brow & 7) << 4));
      __builtin_amdgcn_global_load_lds(
          (const __attribute__((address_space(1))) unsigned int*)(w1tb + srcb),
          (__attribute__((address_space(3))) unsigned int*)(blds + j * 8192 + wid * 1024),
          16, 0, 0);
    }
    __syncthreads();                       // staging complete
    // prefetch next A tile into the other register set (latency hides under MFMA)
    if (kt < 15) {
      const float* gx = x + (size_t)(row0 + arow) * LDIM + (kt + 1) * BK + aq * 16;
      rn[0] = *(const f32x4*)(gx);
      rn[1] = *(const f32x4*)(gx + 4);
      rn[2] = *(const f32x4*)(gx + 8);
      rn[3] = *(const f32x4*)(gx + 12);
    }
    #pragma unroll
    for (int kk = 0; kk < 2; ++kk) {
      short8 af[4], bfr[4];
      #pragma unroll
      for (int m = 0; m < 4; ++m)
        af[m] = *(const short8*)((const char*)xlds + (wr * 64 + m * 16 + cl) * 144 + kk * 64 + g * 16);
      #pragma unroll
      for (int n = 0; n < 4; ++n) {
        int br = wc * 64 + n * 16 + cl;
        bfr[n] = *(const short8*)(blds + br * 128 + ((kk * 64 + g * 16) ^ ((br & 7) << 4)));
      }
      #pragma unroll
      for (int m = 0; m < 4; ++m)
        #pragma unroll
        for (int n = 0; n < 4; ++n)
          acc[m][n] = __builtin_amdgcn_mfma_f32_16x16x32_bf16(af[m], bfr[n], acc[m][n], 0, 0, 0);
      if (zf >= 0) {
        int br = DDIM + zf * 16 + cl;
        short8 zb = *(const short8*)(blds + br * 128 + ((kk * 64 + g * 16) ^ ((br & 7) << 4)));
        #pragma unroll
        for (int m = 0; m < 4; ++m)
          zacc[m] = __builtin_amdgcn_mfma_f32_16x16x32_bf16(af[m], zb, zacc[m], 0, 0, 0);
      }
    }
  };

  #pragma unroll 1
  for (int kt2 = 0; kt2 < 16; kt2 += 2) {
    do_iter(kt2, ra, rb);
    do_iter(kt2 + 1, rb, ra);
  }

  // ---- logits: tanh(z + bz) @ Wa2, reduced across the 16 f-lanes ----
  if (zf >= 0) {
    const int f = zf * 16 + cl;
    const float w2 = Wa2[f];
    const float bzf = bz[f];
    #pragma unroll
    for (int m = 0; m < 4; ++m) {
      float p[4];
      #pragma unroll
      for (int r = 0; r < 4; ++r) {
        float e2 = exp2f((zacc[m][r] + bzf) * 2.8853900817779268f);  // tanh via exp2
        p[r] = (1.f - 2.f / (e2 + 1.f)) * w2;
      }
      #pragma unroll
      for (int mask = 1; mask <= 8; mask <<= 1)
        #pragma unroll
        for (int r = 0; r < 4; ++r)
          p[r] += __shfl_xor(p[r], mask);
      if (cl == 0) {
        #pragma unroll
        for (int r = 0; r < 4; ++r)
          atomicAdd(&logit_s[wr * 64 + m * 16 + g * 4 + r], p[r]);
      }
    }
  }
  __syncthreads();
  if (tid < BM) e_s[tid] = expf(logit_s[tid] + ba2[0]);
  __syncthreads();

  // ---- per-segment weighted accumulation of x@W1 columns + sum of e ----
  const int smin = seg_s[0];
  const int smax = seg_s[BM - 1];
  float ev[16]; int sv[16];
  #pragma unroll
  for (int m = 0; m < 4; ++m)
    #pragma unroll
    for (int r = 0; r < 4; ++r) {
      int rl = wr * 64 + m * 16 + g * 4 + r;
      ev[m * 4 + r] = e_s[rl];
      sv[m * 4 + r] = seg_s[rl];
    }
  for (int s = smin; s <= smax; ++s) {
    float wv[16];
    #pragma unroll
    for (int i = 0; i < 16; ++i) wv[i] = (sv[i] == s) ? ev[i] : 0.f;
    #pragma unroll
    for (int n = 0; n < 4; ++n) {
      float cs = 0.f;
      #pragma unroll
      for (int m = 0; m < 4; ++m)
        #pragma unroll
        for (int r = 0; r < 4; ++r)
          cs += wv[m * 4 + r] * acc[m][n][r];
      cs += __shfl_xor(cs, 16);
      cs += __shfl_xor(cs, 32);
      if (lane < 16) atomicAdd(&acc_eh[s * DDIM + wc * 64 + n * 16 + cl], cs);
    }
    if (wid < 2) {
      int rl = wid * 64 + lane;
      float v = (seg_s[rl] == s) ? e_s[rl] : 0.f;
      #pragma unroll
      for (int mask = 1; mask <= 32; mask <<= 1) v += __shfl_xor(v, mask);
      if (lane == 0) atomicAdd(&accE[s], v);
    }
  }
}

// ---- finalize: M = acc/Sum_e + b1; proj = normalize(M@Wp + bp) ----
__global__ void finalize_k(const float* __restrict__ acc_eh, const float* __restrict__ accE,
                           const float* __restrict__ b1, const float* __restrict__ Wp,
                           const float* __restrict__ bp, float* __restrict__ out) {
  __shared__ float Ml[DDIM];
  const int s = blockIdx.x, t = threadIdx.x;
  const float E = accE[s];
  float m = 0.f;
  if (E > 0.f) m = acc_eh[s * DDIM + t] / E + b1[t];
  out[s * DDIM + t] = m;
  Ml[t] = m;
  __syncthreads();
  if (t < FDIM) {
    float p = bp[t];
    for (int c = 0; c < DDIM; ++c) p += Ml[c] * Wp[c * FDIM + t];
    float n2 = p * p;
    #pragma unroll
    for (int mask = 1; mask <= 16; mask <<= 1) n2 += __shfl_xor(n2, mask);
    out[NSEG * DDIM + s * FDIM + t] = p / fmaxf(sqrtf(n2), 1e-12f);
  }
}

extern "C" void kernel_launch(void* const* d_in, const int* in_sizes, int n_in,
                              void* d_out, int out_size, void* d_ws, size_t ws_size,
                              hipStream_t stream) {
  const float* x   = (const float*)d_in[0];
  const int*   idxs= (const int*)d_in[1];
  const float* W1  = (const float*)d_in[2];
  const float* b1  = (const float*)d_in[3];
  const float* Wa1 = (const float*)d_in[4];
  const float* ba1 = (const float*)d_in[5];
  const float* Wa2 = (const float*)d_in[6];
  const float* ba2 = (const float*)d_in[7];
  const float* Wp  = (const float*)d_in[8];
  const float* bp  = (const float*)d_in[9];
  float* out = (float*)d_out;

  char* ws = (char*)d_ws;
  unsigned short* w1t = (unsigned short*)ws;          // 320*1024 bf16 = 655360 B
  float* bz     = (float*)(ws + 655360);              // 32 f32
  float* acc_eh = (float*)(ws + 655488);              // 64*256 f32
  float* accE   = (float*)(ws + 721024);              // 64 f32

  const int n = in_sizes[1];                          // 262144 rows
  prep_w1t<<<LDIM, DDIM, 0, stream>>>(W1, Wa1, w1t);
  prep_misc<<<NSEG, DDIM, 0, stream>>>(b1, Wa1, ba1, bz, acc_eh, accE);
  fused_main<<<n / BM, 512, 0, stream>>>(x, idxs, w1t, bz, Wa2, ba2, acc_eh, accE);
  finalize_k<<<NSEG, DDIM, 0, stream>>>(acc_eh, accE, b1, Wp, bp, out);
}